// Round 22
// baseline (426.692 us; speedup 1.0000x reference)
//
#include <hip/hip_runtime.h>
#include <math.h>

#define NBIN 49
#define NOUT 105   // 21 cls + 84 reg
#define NCLS 21
#define BM 64
#define BK 64
#define MTILES 16  // 1024 / BM
#define KT 8       // channel slices, one per XCD (id & 7)

typedef __attribute__((ext_vector_type(4))) float f32x4;
typedef __attribute__((ext_vector_type(8))) short bf16x8;

#define YBYTES  33554432u   // 2*4096*1024*4
#define WPBYTES 11239424u   // 49*16*7168*2

__device__ __forceinline__ unsigned short bf16rne(float x) {
  unsigned u = __float_as_uint(x);
  u = (u + 0x7FFFu + ((u >> 16) & 1u)) >> 16;
  return (unsigned short)u;
}

// ---------------- K1: transpose h[b][c][y][x] -> hT[b][(y*64+x)][c] ----------------
__global__ __launch_bounds__(256) void k_transpose(const float* __restrict__ h,
                                                   float* __restrict__ hT) {
  __shared__ float tile[32][33];
  const int b  = blockIdx.z;
  const int s0 = blockIdx.x * 32;   // spatial
  const int c0 = blockIdx.y * 32;   // channel
  const int tx = threadIdx.x & 31, ty = threadIdx.x >> 5;  // ty 0..7
#pragma unroll
  for (int i = 0; i < 4; ++i) {
    int c = c0 + ty + i * 8;
    tile[ty + i * 8][tx] = h[((size_t)b * 1024 + c) * 4096 + s0 + tx];
  }
  __syncthreads();
#pragma unroll
  for (int i = 0; i < 4; ++i) {
    int s = s0 + ty + i * 8;
    hT[((size_t)b * 4096 + s) * 1024 + c0 + tx] = tile[tx][ty + i * 8];
  }
}

// ---------------- K2: in-place y-prefix-sum on hT (channels-last) ----------------
__global__ __launch_bounds__(256) void k_ycumsum(float* __restrict__ hT) {
  const int c = blockIdx.x * 256 + threadIdx.x;  // 0..1023
  const int x = blockIdx.y;                      // 0..63
  const int b = blockIdx.z;                      // 0..1
  float* p = hT + ((size_t)b * 4096 + x) * 1024 + c;
  float run = 0.f;
#pragma unroll 4
  for (int y = 0; y < 64; ++y) {
    run += p[(size_t)y * 65536];
    p[(size_t)y * 65536] = run;
  }
}

// ---------------- K2c: pre-pack W -> bf16 swizzled 64-ch blocks (ws-gated) ----------------
// Image byte-identical to the in-kernel LDS staging result (proven R19).
__global__ __launch_bounds__(256) void k_wpack(const float* __restrict__ Wc,
                                               const float* __restrict__ Wl,
                                               unsigned short* __restrict__ Wp) {
  const int bin = blockIdx.x, chunk = blockIdx.y, t = threadIdx.x;
  const int c0 = chunk * 64;
  unsigned short* dst = Wp + (size_t)(bin * 16 + chunk) * 7168;
#pragma unroll
  for (int i = 0; i < 7; ++i) {
    int idx = t + i * 256;        // 0..1791
    int row = idx >> 4;
    int cq  = idx & 15;
    float4 v = {0.f, 0.f, 0.f, 0.f};
    if (row < NCLS)
      v = *(const float4*)&Wc[(size_t)(row * 49 + bin) * 1024 + c0 + cq * 4];
    else if (row < NOUT)
      v = *(const float4*)&Wl[(size_t)((row - NCLS) * 49 + bin) * 1024 + c0 + cq * 4];
    unsigned p0 = (unsigned)bf16rne(v.x) | ((unsigned)bf16rne(v.y) << 16);
    unsigned p1 = (unsigned)bf16rne(v.z) | ((unsigned)bf16rne(v.w) << 16);
    *(uint2*)&dst[(row * BK + cq * 4) ^ ((row & 7) << 3)] = make_uint2(p0, p1);
  }
}

// ---------------- K3: fused PSRoI-pool (y-prefix) + bf16 MFMA GEMM ----------------
// 1-D grid 6272 = 16 mt x 49 bin x 8 kt; kt = id&7 -> XCD-affine channel slices.
__global__ __launch_bounds__(256) void k_pool_gemm(
    const float* __restrict__ Y, const float* __restrict__ rois,
    const int* __restrict__ ridx, const float* __restrict__ Wc,
    const float* __restrict__ bc, const float* __restrict__ Wl,
    const float* __restrict__ bl, const unsigned short* __restrict__ Wp,
    const int useWp, float* out) {
  const int id = blockIdx.x;
  const int kt = id & 7;          // channel slice (XCD-affine under round-robin)
  const int j  = id >> 3;         // 0..783
  const int bin = j % NBIN;
  const int mt  = j / NBIN;
  const int bi = bin / 7, bj = bin % 7;
  const int t = threadIdx.x;

  __shared__ unsigned short AsS[BM * BK];        // [64][64] bf16, XOR-swizzled
  __shared__ unsigned short WlS[(NOUT + 7) * BK];// [112][64] bf16, XOR-swizzled
  __shared__ int   wsS[BM], weS[BM], hiS[BM], loS[BM], bS[BM];
  __shared__ float scS[BM], mkS[BM], lsS[BM];

  if (t < BM) {
    int r = mt * BM + t;
    int x1 = (int)floorf(rois[r * 4 + 0] * 0.0625f + 0.5f);
    int y1 = (int)floorf(rois[r * 4 + 1] * 0.0625f + 0.5f);
    int x2 = (int)floorf(rois[r * 4 + 2] * 0.0625f + 0.5f);
    int y2 = (int)floorf(rois[r * 4 + 3] * 0.0625f + 0.5f);
    const float INV7 = 1.0f / 7.0f;        // reciprocal-multiply (np-ref semantics)
    float bw = (float)max(x2 - x1, 1) * INV7;
    float bh = (float)max(y2 - y1, 1) * INV7;
    int ws_ = min(max((int)floorf((float)bj * bw) + x1, 0), 64);
    int we_ = min(max((int)ceilf((float)(bj + 1) * bw) + x1, 0), 64);
    int hs_ = min(max((int)floorf((float)bi * bh) + y1, 0), 64);
    int he_ = min(max((int)ceilf((float)(bi + 1) * bh) + y1, 0), 64);
    int area = (he_ - hs_) * (we_ - ws_);
    bool m = area > 0;
    scS[t] = m ? 1.0f / (49.0f * (float)area) : 0.0f;
    mkS[t] = (m && kt == 0) ? (1.0f / 49.0f) : 0.0f;  // bias once (kt==0)
    wsS[t] = ws_;
    weS[t] = m ? we_ : ws_;                  // empty loop when masked
    hiS[t] = m ? (he_ - 1) * 64 : 0;
    loS[t] = max(hs_ - 1, 0) * 64;
    lsS[t] = (hs_ > 0) ? 1.0f : 0.0f;
    bS[t]  = ridx[r];
  }
  __syncthreads();

  const int tx = t & 15, ty = t >> 4;   // staging decomposition
  const int ty4 = ty * 4;
  const int w = t >> 6;                 // wave id 0..3 (m-tile)
  const int l = t & 63;
  const int lrow = l & 15, lk8 = (l >> 4) * 8;

  f32x4 acc[7];
#pragma unroll
  for (int nt = 0; nt < 7; ++nt) acc[nt] = (f32x4){0.f, 0.f, 0.f, 0.f};

  for (int ci = 0; ci < 2; ++ci) {
    const int c0i = kt * 2 + ci;
    const int c0 = c0i * 64;
    // ---- stage A: window sum from y-prefix rows -> bf16 LDS (swizzled) ----
#pragma unroll
    for (int rr = 0; rr < 4; ++rr) {
      int r = ty4 + rr;
      float s0 = 0.f, s1 = 0.f, s2 = 0.f, s3 = 0.f;
      const int ws = wsS[r], we = weS[r], hi = hiS[r], lo = loS[r];
      const float ls = lsS[r];
      const float* baseY = Y + (size_t)bS[r] * 4096 * 1024 + c0 + tx * 4;
      for (int x = ws; x < we; ++x) {
        const float4 vh = *(const float4*)&baseY[(size_t)(hi + x) * 1024];
        const float4 vl = *(const float4*)&baseY[(size_t)(lo + x) * 1024];
        s0 += vh.x - ls * vl.x;
        s1 += vh.y - ls * vl.y;
        s2 += vh.z - ls * vl.z;
        s3 += vh.w - ls * vl.w;
      }
      float sc = scS[r];
      unsigned p0 = (unsigned)bf16rne(s0 * sc) | ((unsigned)bf16rne(s1 * sc) << 16);
      unsigned p1 = (unsigned)bf16rne(s2 * sc) | ((unsigned)bf16rne(s3 * sc) << 16);
      int idx = (r * BK + tx * 4) ^ ((r & 7) << 3);
      *(uint2*)&AsS[idx] = make_uint2(p0, p1);
    }
    // ---- stage W ----
    if (useWp) {
      const uint2* srcW = (const uint2*)(Wp + (size_t)(bin * 16 + c0i) * 7168);
#pragma unroll
      for (int i = 0; i < 7; ++i) {
        int idx = t + i * 256;    // verbatim pre-swizzled block copy
        *(uint2*)&WlS[idx * 4] = srcW[idx];
      }
    } else {
#pragma unroll
      for (int it = 0; it < 7; ++it) {
        int idx = t + it * 256;       // 0..1791, bijective over (row, cq)
        int row = idx >> 4;
        int cq  = idx & 15;
        float4 v = {0.f, 0.f, 0.f, 0.f};
        if (row < NCLS)
          v = *(const float4*)&Wc[(size_t)(row * 49 + bin) * 1024 + c0 + cq * 4];
        else if (row < NOUT)
          v = *(const float4*)&Wl[(size_t)((row - NCLS) * 49 + bin) * 1024 + c0 + cq * 4];
        unsigned p0 = (unsigned)bf16rne(v.x) | ((unsigned)bf16rne(v.y) << 16);
        unsigned p1 = (unsigned)bf16rne(v.z) | ((unsigned)bf16rne(v.w) << 16);
        int widx = (row * BK + cq * 4) ^ ((row & 7) << 3);
        *(uint2*)&WlS[widx] = make_uint2(p0, p1);
      }
    }
    __syncthreads();

    // ---- MFMA: wave w owns m-tile w (16 RoIs) x 7 n-tiles, K=64 ----
    bf16x8 af[2];
#pragma unroll
    for (int ks = 0; ks < 2; ++ks) {
      int r = w * 16 + lrow;
      int k = ks * 32 + lk8;
      int ai = (r * BK + k) ^ ((r & 7) << 3);
      af[ks] = *(const bf16x8*)&AsS[ai];
    }
#pragma unroll
    for (int nt = 0; nt < 7; ++nt) {
#pragma unroll
      for (int ks = 0; ks < 2; ++ks) {
        int row = nt * 16 + lrow;
        int k = ks * 32 + lk8;
        int bix = (row * BK + k) ^ ((row & 7) << 3);
        bf16x8 bf = *(const bf16x8*)&WlS[bix];
        acc[nt] = __builtin_amdgcn_mfma_f32_16x16x32_bf16(af[ks], bf, acc[nt], 0, 0, 0);
      }
    }
    __syncthreads();
  }

  // ---- epilogue: bias + atomic accumulate. D layout: n=l&15, m=4*(l>>4)+b ----
#pragma unroll
  for (int nt = 0; nt < 7; ++nt) {
    int o = nt * 16 + (l & 15);
    if (o < NOUT) {
      float bias = (o < NCLS) ? bc[o * 49 + bin] : bl[(o - NCLS) * 49 + bin];
#pragma unroll
      for (int b = 0; b < 4; ++b) {
        int r_loc = w * 16 + 4 * (l >> 4) + b;
        int gr = mt * BM + r_loc;
        float val = acc[nt][b] + mkS[r_loc] * bias;
        if (o < NCLS)
          atomicAdd(&out[gr * NCLS + o], val);
        else
          atomicAdd(&out[1024 * NCLS + gr * 84 + (o - NCLS)], val);
      }
    }
  }
}

extern "C" void kernel_launch(void* const* d_in, const int* in_sizes, int n_in,
                              void* d_out, int out_size, void* d_ws, size_t ws_size,
                              hipStream_t stream) {
  const float* h    = (const float*)d_in[0];
  const float* rois = (const float*)d_in[1];
  const int*   ridx = (const int*)d_in[2];
  const float* Wc   = (const float*)d_in[3];
  const float* bc   = (const float*)d_in[4];
  const float* Wl   = (const float*)d_in[5];
  const float* bl   = (const float*)d_in[6];
  float* out = (float*)d_out;

  float* hT = (float*)d_ws;   // 33.55 MB (becomes y-prefix Y in-place) — proven
  unsigned short* Wp = (unsigned short*)((char*)d_ws + YBYTES);
  const int useWp = (ws_size >= (size_t)YBYTES + WPBYTES) ? 1 : 0;

  hipMemsetAsync(out, 0, (size_t)out_size * sizeof(float), stream);
  if (useWp) k_wpack<<<dim3(NBIN, 16), 256, 0, stream>>>(Wc, Wl, Wp);
  k_transpose<<<dim3(128, 32, 2), 256, 0, stream>>>(h, hT);
  k_ycumsum<<<dim3(4, 64, 2), 256, 0, stream>>>(hT);
  k_pool_gemm<<<dim3(MTILES * NBIN * KT), 256, 0, stream>>>(hT, rois, ridx, Wc, bc, Wl, bl,
                                                            Wp, useWp, out);
}

// Round 23
// 165.955 us; speedup vs baseline: 2.5711x; 2.5711x over previous
//
#include <hip/hip_runtime.h>
#include <math.h>

#define NBIN 49
#define NOUT 105   // 21 cls + 84 reg
#define NCLS 21
#define BM 64
#define BK 64
#define MTILES 16  // 1024 / BM

typedef __attribute__((ext_vector_type(4))) float f32x4;
typedef __attribute__((ext_vector_type(8))) short bf16x8;

__device__ __forceinline__ unsigned short bf16rne(float x) {
  unsigned u = __float_as_uint(x);
  u = (u + 0x7FFFu + ((u >> 16) & 1u)) >> 16;
  return (unsigned short)u;
}

// ---------------- K1: transpose h[b][c][y][x] -> hT[b][(y*64+x)][c] ----------------
__global__ __launch_bounds__(256) void k_transpose(const float* __restrict__ h,
                                                   float* __restrict__ hT) {
  __shared__ float tile[32][33];
  const int b  = blockIdx.z;
  const int s0 = blockIdx.x * 32;   // spatial
  const int c0 = blockIdx.y * 32;   // channel
  const int tx = threadIdx.x & 31, ty = threadIdx.x >> 5;  // ty 0..7
#pragma unroll
  for (int i = 0; i < 4; ++i) {
    int c = c0 + ty + i * 8;
    tile[ty + i * 8][tx] = h[((size_t)b * 1024 + c) * 4096 + s0 + tx];
  }
  __syncthreads();
#pragma unroll
  for (int i = 0; i < 4; ++i) {
    int s = s0 + ty + i * 8;
    hT[((size_t)b * 4096 + s) * 1024 + c0 + tx] = tile[tx][ty + i * 8];
  }
}

// ---------------- K2: in-place y-prefix-sum on hT (channels-last) ----------------
__global__ __launch_bounds__(256) void k_ycumsum(float* __restrict__ hT) {
  const int c = blockIdx.x * 256 + threadIdx.x;  // 0..1023
  const int x = blockIdx.y;                      // 0..63
  const int b = blockIdx.z;                      // 0..1
  float* p = hT + ((size_t)b * 4096 + x) * 1024 + c;
  float run = 0.f;
#pragma unroll 4
  for (int y = 0; y < 64; ++y) {
    run += p[(size_t)y * 65536];
    p[(size_t)y * 65536] = run;
  }
}

// ---------------- K3: fused PSRoI-pool (via y-prefix) + bf16 MFMA GEMM ----------------
__global__ __launch_bounds__(256) void k_pool_gemm(
    const float* __restrict__ Y, const float* __restrict__ rois,
    const int* __restrict__ ridx, const float* __restrict__ Wc,
    const float* __restrict__ bc, const float* __restrict__ Wl,
    const float* __restrict__ bl, float* out) {
  const int mt  = blockIdx.x;
  const int bin = blockIdx.y;
  const int bi = bin / 7, bj = bin % 7;
  const int t = threadIdx.x;

  __shared__ unsigned short AsS[BM * BK];        // [64][64] bf16, XOR-swizzled
  __shared__ unsigned short WlS[(NOUT + 7) * BK];// [112][64] bf16, XOR-swizzled
  __shared__ int   wsS[BM], weS[BM], hiS[BM], loS[BM], bS[BM];
  __shared__ float scS[BM], mkS[BM], lsS[BM];

  if (t < BM) {
    int r = mt * BM + t;
    int x1 = (int)floorf(rois[r * 4 + 0] * 0.0625f + 0.5f);
    int y1 = (int)floorf(rois[r * 4 + 1] * 0.0625f + 0.5f);
    int x2 = (int)floorf(rois[r * 4 + 2] * 0.0625f + 0.5f);
    int y2 = (int)floorf(rois[r * 4 + 3] * 0.0625f + 0.5f);
    const float INV7 = 1.0f / 7.0f;        // reciprocal-multiply (np-ref semantics)
    float bw = (float)max(x2 - x1, 1) * INV7;
    float bh = (float)max(y2 - y1, 1) * INV7;
    int ws_ = min(max((int)floorf((float)bj * bw) + x1, 0), 64);
    int we_ = min(max((int)ceilf((float)(bj + 1) * bw) + x1, 0), 64);
    int hs_ = min(max((int)floorf((float)bi * bh) + y1, 0), 64);
    int he_ = min(max((int)ceilf((float)(bi + 1) * bh) + y1, 0), 64);
    int area = (he_ - hs_) * (we_ - ws_);
    bool m = area > 0;
    scS[t] = m ? 1.0f / (49.0f * (float)area) : 0.0f;
    mkS[t] = m ? (1.0f / 49.0f) : 0.0f;
    wsS[t] = ws_;
    weS[t] = m ? we_ : ws_;                  // empty loop when masked
    hiS[t] = m ? (he_ - 1) * 64 : 0;
    loS[t] = max(hs_ - 1, 0) * 64;
    lsS[t] = (hs_ > 0) ? 1.0f : 0.0f;
    bS[t]  = ridx[r];
  }
  __syncthreads();

  const int tx = t & 15, ty = t >> 4;   // staging decomposition
  const int ty4 = ty * 4;
  const int w = t >> 6;                 // wave id 0..3 (m-tile)
  const int l = t & 63;
  const int lrow = l & 15, lk8 = (l >> 4) * 8;

  f32x4 acc[7];
#pragma unroll
  for (int nt = 0; nt < 7; ++nt) acc[nt] = (f32x4){0.f, 0.f, 0.f, 0.f};

  for (int c0 = 0; c0 < 1024; c0 += BK) {
    // ---- stage A: window sum from y-prefix rows -> bf16 LDS (swizzled) ----
#pragma unroll
    for (int rr = 0; rr < 4; ++rr) {
      int r = ty4 + rr;
      float s0 = 0.f, s1 = 0.f, s2 = 0.f, s3 = 0.f;
      const int ws = wsS[r], we = weS[r], hi = hiS[r], lo = loS[r];
      const float ls = lsS[r];
      const float* baseY = Y + (size_t)bS[r] * 4096 * 1024 + c0 + tx * 4;
      for (int x = ws; x < we; ++x) {
        const float4 vh = *(const float4*)&baseY[(size_t)(hi + x) * 1024];
        const float4 vl = *(const float4*)&baseY[(size_t)(lo + x) * 1024];
        s0 += vh.x - ls * vl.x;
        s1 += vh.y - ls * vl.y;
        s2 += vh.z - ls * vl.z;
        s3 += vh.w - ls * vl.w;
      }
      float sc = scS[r];
      unsigned p0 = (unsigned)bf16rne(s0 * sc) | ((unsigned)bf16rne(s1 * sc) << 16);
      unsigned p1 = (unsigned)bf16rne(s2 * sc) | ((unsigned)bf16rne(s3 * sc) << 16);
      int idx = (r * BK + tx * 4) ^ ((r & 7) << 3);
      *(uint2*)&AsS[idx] = make_uint2(p0, p1);
    }
    // ---- stage W: 112 rows x 64 ch -> bf16 LDS (swizzled; rows >=105 zero) ----
#pragma unroll
    for (int it = 0; it < 7; ++it) {
      int idx = t + it * 256;       // 0..1791, bijective over (row, cq)
      int row = idx >> 4;
      int cq  = idx & 15;
      float4 v = {0.f, 0.f, 0.f, 0.f};
      if (row < NCLS)
        v = *(const float4*)&Wc[(size_t)(row * 49 + bin) * 1024 + c0 + cq * 4];
      else if (row < NOUT)
        v = *(const float4*)&Wl[(size_t)((row - NCLS) * 49 + bin) * 1024 + c0 + cq * 4];
      unsigned p0 = (unsigned)bf16rne(v.x) | ((unsigned)bf16rne(v.y) << 16);
      unsigned p1 = (unsigned)bf16rne(v.z) | ((unsigned)bf16rne(v.w) << 16);
      int widx = (row * BK + cq * 4) ^ ((row & 7) << 3);
      *(uint2*)&WlS[widx] = make_uint2(p0, p1);
    }
    __syncthreads();

    // ---- MFMA: wave w owns m-tile w (16 RoIs) x 7 n-tiles, K=64 ----
    bf16x8 af[2];
#pragma unroll
    for (int ks = 0; ks < 2; ++ks) {
      int r = w * 16 + lrow;
      int k = ks * 32 + lk8;
      int ai = (r * BK + k) ^ ((r & 7) << 3);
      af[ks] = *(const bf16x8*)&AsS[ai];
    }
#pragma unroll
    for (int nt = 0; nt < 7; ++nt) {
#pragma unroll
      for (int ks = 0; ks < 2; ++ks) {
        int row = nt * 16 + lrow;
        int k = ks * 32 + lk8;
        int bix = (row * BK + k) ^ ((row & 7) << 3);
        bf16x8 bf = *(const bf16x8*)&WlS[bix];
        acc[nt] = __builtin_amdgcn_mfma_f32_16x16x32_bf16(af[ks], bf, acc[nt], 0, 0, 0);
      }
    }
    __syncthreads();
  }

  // ---- epilogue: bias + atomic accumulate. D layout: n=l&15, m=4*(l>>4)+b ----
#pragma unroll
  for (int nt = 0; nt < 7; ++nt) {
    int o = nt * 16 + (l & 15);
    if (o < NOUT) {
      float bias = (o < NCLS) ? bc[o * 49 + bin] : bl[(o - NCLS) * 49 + bin];
#pragma unroll
      for (int b = 0; b < 4; ++b) {
        int r_loc = w * 16 + 4 * (l >> 4) + b;
        int gr = mt * BM + r_loc;
        float val = acc[nt][b] + mkS[r_loc] * bias;
        if (o < NCLS)
          atomicAdd(&out[gr * NCLS + o], val);
        else
          atomicAdd(&out[1024 * NCLS + gr * 84 + (o - NCLS)], val);
      }
    }
  }
}

extern "C" void kernel_launch(void* const* d_in, const int* in_sizes, int n_in,
                              void* d_out, int out_size, void* d_ws, size_t ws_size,
                              hipStream_t stream) {
  const float* h    = (const float*)d_in[0];
  const float* rois = (const float*)d_in[1];
  const int*   ridx = (const int*)d_in[2];
  const float* Wc   = (const float*)d_in[3];
  const float* bc   = (const float*)d_in[4];
  const float* Wl   = (const float*)d_in[5];
  const float* bl   = (const float*)d_in[6];
  float* out = (float*)d_out;

  float* hT = (float*)d_ws;   // 33.55 MB (becomes y-prefix Y in-place)

  hipMemsetAsync(out, 0, (size_t)out_size * sizeof(float), stream);
  k_transpose<<<dim3(128, 32, 2), 256, 0, stream>>>(h, hT);
  k_ycumsum<<<dim3(4, 64, 2), 256, 0, stream>>>(hT);
  k_pool_gemm<<<dim3(MTILES, NBIN), 256, 0, stream>>>(hT, rois, ridx, Wc, bc, Wl, bl, out);
}